// Round 1
// baseline (154.939 us; speedup 1.0000x reference)
//
#include <hip/hip_runtime.h>

// SymmetryControl: B=16, C=96, H=96, W=96 fp32.
// out[b,c,h,i] = num/den, 6 taps of the same 96-wide row, gated by sigmoid(s[b,:]).
//
// R5 theory: R4 (one tile per block, __syncthreads between load and use) is
// latency-bound: every block pays a full global-load latency against ~300 cyc of
// compute; no pipe exceeds 30%. Fix: persistent blocks (4 tiles each) with
// double-buffered LDS, ONE raw s_barrier per tile (lgkmcnt(0) only — vmcnt left
// in flight), and the next tile's x/w prefetched into registers before the
// barrier so load latency hides under the previous tile's compute (T14 idiom).
// Also LSTR 100 -> 120: 120 % 32 == 24 makes the 3 rows a wave spans land on
// bank offsets {0,24,16} -> perfect free 2-way spread (was 3-way, ~2 cyc/read).

#define WDIM 96
#define ROWS 16          // rows per LDS tile
#define RPB  9216        // rows per batch (C*H)
#define LSTR 120         // padded LDS row stride: 120%32==24 -> conflict-free 2-way
#define GRID 2304        // 9216 tiles / 2304 blocks = 4 tiles per block

__global__ __launch_bounds__(24 * ROWS)
void symctl_kernel(const float* __restrict__ x,
                   const float* __restrict__ s,
                   const float* __restrict__ w,
                   float* __restrict__ out,
                   int ntiles) {
    __shared__ float pb[2][ROWS][LSTR];   // x*w products
    __shared__ float wb[2][ROWS][LSTR];   // weights

    const int t  = threadIdx.x;           // 0..23
    const int ry = threadIdx.y;           // 0..ROWS-1
    const int gstride = gridDim.x;

    int tile = blockIdx.x;

    // ---- prologue: load first tile into registers ----
    {
        const size_t row = (size_t)tile * ROWS + ry;
        // (loads below)
    }
    const size_t row0 = (size_t)tile * ROWS + ry;
    float4 xa = ((const float4*)(x + row0 * WDIM))[t];
    float4 wa = ((const float4*)(w + row0 * WDIM))[t];

    int buf = 0;
    bool more = true;
    do {
        const int cur = tile;

        // ---- stage current tile into LDS[buf] ----
        float4 p4;
        p4.x = xa.x * wa.x; p4.y = xa.y * wa.y;
        p4.z = xa.z * wa.z; p4.w = xa.w * wa.w;
        *(float4*)&pb[buf][ry][4 * t] = p4;
        *(float4*)&wb[buf][ry][4 * t] = wa;

        // ---- prefetch next tile into registers (stays in flight across barrier) ----
        tile += gstride;
        more = (tile < ntiles);
        if (more) {
            const size_t nrow = (size_t)tile * ROWS + ry;
            xa = ((const float4*)(x + nrow * WDIM))[t];
            wa = ((const float4*)(w + nrow * WDIM))[t];
        }

        // ---- per-tile sigmoid gates (uniform scalar work, overlaps the stage) ----
        const int b = (cur * ROWS) / RPB;     // uniform batch index
        const float* sb = s + b * 5;
        const float sg0 = 1.0f / (1.0f + __expf(-sb[0]));
        const float sg1 = 1.0f / (1.0f + __expf(-sb[1]));
        const float sg2 = 1.0f / (1.0f + __expf(-sb[2]));
        const float sg3 = 1.0f / (1.0f + __expf(-sb[3]));
        const float sg4 = 1.0f / (1.0f + __expf(-sb[4]));

        // LDS writes drained; global prefetch loads deliberately left in flight
        // (__syncthreads would emit vmcnt(0) and kill the overlap).
        asm volatile("s_waitcnt lgkmcnt(0)" ::: "memory");
        __builtin_amdgcn_s_barrier();

        // ---- phase 2: quarter-structure gather, 4 outputs per thread ----
        const int r  = t;
        const int rm = 23 - t;
        const float* pr = &pb[buf][ry][0];
        const float* wr = &wb[buf][ry][0];

        float pq[4], aq[4], pP[4], aP[4];
#pragma unroll
        for (int q = 0; q < 4; ++q) {
            pq[q] = pr[24 * q + r];
            aq[q] = wr[24 * q + r];
            pP[q] = pr[24 * q + rm];
            aP[q] = wr[24 * q + rm];
        }

        float* orow = out + (size_t)((size_t)cur * ROWS + ry) * WDIM + r;
#pragma unroll
        for (int q = 0; q < 4; ++q) {
            const int i1 = (q + 3) & 3;   // q-1
            const int i2 = (q + 2) & 3;   // q-2
            const int i3 = (q + 1) & 3;   // q-3
            const int i4 = (4 - q) & 3;   // -q
            const int i5 = (5 - q) & 3;   // 1-q

            float num = pq[q];
            num = fmaf(sg0, pq[i1], num);
            num = fmaf(sg1, pq[i2], num);
            num = fmaf(sg2, pq[i3], num);
            num = fmaf(sg3, pP[i4], num);
            num = fmaf(sg4, pP[i5], num);

            float den = aq[q];
            den = fmaf(sg0, aq[i1], den);
            den = fmaf(sg1, aq[i2], den);
            den = fmaf(sg2, aq[i3], den);
            den = fmaf(sg3, aP[i4], den);
            den = fmaf(sg4, aP[i5], den);

            orow[24 * q] = num * __builtin_amdgcn_rcpf(den);
        }

        buf ^= 1;
    } while (more);
}

extern "C" void kernel_launch(void* const* d_in, const int* in_sizes, int n_in,
                              void* d_out, int out_size, void* d_ws, size_t ws_size,
                              hipStream_t stream) {
    const float* x = (const float*)d_in[0];
    const float* s = (const float*)d_in[1];
    const float* w = (const float*)d_in[2];
    float* out = (float*)d_out;

    const int n_rows = in_sizes[0] / (WDIM * 4);   // bytes -> rows? (see below)
    // in_sizes is element count in previous harness usage: keep prior convention.
    const int n_rows_elems = in_sizes[0] / WDIM;   // rows if in_sizes[0] is float count
    const int ntiles = n_rows_elems / ROWS;        // 9216 for the reference shape

    const int grid = (ntiles < GRID) ? ntiles : GRID;

    dim3 block(24, ROWS);
    symctl_kernel<<<grid, block, 0, stream>>>(x, s, w, out, ntiles);
}